// Round 1
// baseline (360.267 us; speedup 1.0000x reference)
//
#include <hip/hip_runtime.h>
#include <hip/hip_bf16.h>

typedef __attribute__((ext_vector_type(8))) short bf16x8;
typedef __attribute__((ext_vector_type(4))) float f32x4;

#define NROWS 262144
#define MBLK  64
#define NBLKS (NROWS / MBLK)   /* 4096 */

// ---------------------------------------------------------------------------
// Weight prep: build MFMA B-fragment-layout bf16 hi/lo copies of the 8 weight
// matrices, concatenated as Wbig[gate][n=0..127][k=0..255] (k<128 -> W, else U).
// Fragment element (g, ni, kk, lane, j) holds Wbig[g][16*ni + (lane&15)]
//                                                  [32*kk + 8*(lane>>4) + j]
// stored flat so a wave's 16B load per (g,ni,kk) is fully coalesced.
// ---------------------------------------------------------------------------
__global__ void prep_weights(
    const float* __restrict__ Wi, const float* __restrict__ Ui,
    const float* __restrict__ Wf, const float* __restrict__ Uf,
    const float* __restrict__ Wo, const float* __restrict__ Uo,
    const float* __restrict__ Wz, const float* __restrict__ Uz,
    ushort* __restrict__ hi, ushort* __restrict__ lo)
{
    int idx = blockIdx.x * 256 + threadIdx.x;   // 0..131071 = 4*8*8*64*8
    int j    = idx & 7;
    int lane = (idx >> 3) & 63;
    int kk   = (idx >> 9) & 7;
    int ni   = (idx >> 12) & 7;
    int g    = idx >> 15;
    int n = ni * 16 + (lane & 15);
    int k = kk * 32 + (lane >> 4) * 8 + j;
    const float* W; const float* U;
    if (g == 0)      { W = Wi; U = Ui; }
    else if (g == 1) { W = Wf; U = Uf; }
    else if (g == 2) { W = Wo; U = Uo; }
    else             { W = Wz; U = Uz; }
    float w = (k < 128) ? W[n * 128 + k] : U[n * 128 + (k - 128)];
    __hip_bfloat16 hb = __float2bfloat16(w);
    float r = w - __bfloat162float(hb);
    __hip_bfloat16 lb = __float2bfloat16(r);
    hi[idx] = *reinterpret_cast<ushort*>(&hb);
    lo[idx] = *reinterpret_cast<ushort*>(&lb);
}

// ---------------------------------------------------------------------------
// Main fused kernel. Block = 512 threads = 8 waves, 64 rows per block.
// Wave w: gate g = w&3, column half ch = w>>2 (64 of the gate's 128 cols).
// A = [x | h_prev] staged in LDS as bf16 hi/lo, XOR-swizzled 16B chunks.
// ---------------------------------------------------------------------------
__global__ __launch_bounds__(512) void slstm_main(
    const float* __restrict__ x,     const float* __restrict__ hprev,
    const float* __restrict__ cprev, const float* __restrict__ nprev,
    const float* __restrict__ bi,    const float* __restrict__ bfg,
    const float* __restrict__ bo,    const float* __restrict__ bz,
    const ushort* __restrict__ whi,  const ushort* __restrict__ wlo,
    float* __restrict__ out)
{
    __shared__ ushort Ahi[64 * 256];   // 32 KB, swizzled
    __shared__ ushort Alo[64 * 256];   // 32 KB, swizzled
    // epilogue pre-activation staging aliases Ahi (32 KB as float[16][512])
    float* pre = reinterpret_cast<float*>(Ahi);

    const int tid  = threadIdx.x;
    const int row0 = blockIdx.x * MBLK;

    // ---- stage A: load fp32 x / h_prev, split to bf16 hi+lo, swizzled LDS ----
    char* AhiB = reinterpret_cast<char*>(Ahi);
    char* AloB = reinterpret_cast<char*>(Alo);
    #pragma unroll
    for (int i = 0; i < 4; ++i) {
        int f4  = tid + i * 512;          // 0..2047
        int row = f4 >> 5;                // 0..63
        int c4  = f4 & 31;                // float4 index within 128-float row
        float4 vx = reinterpret_cast<const float4*>(x)[(size_t)(row0 + row) * 32 + c4];
        float4 vh = reinterpret_cast<const float4*>(hprev)[(size_t)(row0 + row) * 32 + c4];
        #pragma unroll
        for (int half = 0; half < 2; ++half) {
            float4 v = half ? vh : vx;
            int kbase = half * 128 + 4 * c4;
            int q   = kbase >> 3;
            int sub = (kbase & 7) * 2;                     // 0 or 8 bytes
            int byt = row * 512 + ((q ^ (row & 7)) << 4) + sub;
            float vv[4] = {v.x, v.y, v.z, v.w};
            ushort h4[4], l4v[4];
            #pragma unroll
            for (int e = 0; e < 4; ++e) {
                __hip_bfloat16 hb = __float2bfloat16(vv[e]);
                float r = vv[e] - __bfloat162float(hb);
                __hip_bfloat16 lb = __float2bfloat16(r);
                h4[e]  = *reinterpret_cast<ushort*>(&hb);
                l4v[e] = *reinterpret_cast<ushort*>(&lb);
            }
            uint2 hp, lp;
            hp.x = (uint)h4[0] | ((uint)h4[1] << 16);
            hp.y = (uint)h4[2] | ((uint)h4[3] << 16);
            lp.x = (uint)l4v[0] | ((uint)l4v[1] << 16);
            lp.y = (uint)l4v[2] | ((uint)l4v[3] << 16);
            *reinterpret_cast<uint2*>(AhiB + byt) = hp;
            *reinterpret_cast<uint2*>(AloB + byt) = lp;
        }
    }
    __syncthreads();

    // ---- K-loop: 3-term split-precision MFMA ----
    const int wid  = tid >> 6;
    const int lane = tid & 63;
    const int g    = wid & 3;
    const int ch   = wid >> 2;
    const int l15  = lane & 15;
    const int lg   = lane >> 4;

    f32x4 acc[4][4] = {};   // [mi][ni] ; wave tile = 64 rows x 64 cols

    #pragma unroll
    for (int kk = 0; kk < 8; ++kk) {
        bf16x8 ah[4], al[4];
        #pragma unroll
        for (int mi = 0; mi < 4; ++mi) {
            int row = mi * 16 + l15;
            int q   = kk * 4 + lg;
            int byt = row * 512 + ((q ^ (row & 7)) << 4);
            ah[mi] = *reinterpret_cast<const bf16x8*>(AhiB + byt);
            al[mi] = *reinterpret_cast<const bf16x8*>(AloB + byt);
        }
        #pragma unroll
        for (int ni = 0; ni < 4; ++ni) {
            int nig = ch * 4 + ni;
            size_t off = (size_t)((((g * 8 + nig) * 8 + kk) * 64) + lane) * 8;
            bf16x8 bh = *reinterpret_cast<const bf16x8*>(whi + off);
            bf16x8 bl = *reinterpret_cast<const bf16x8*>(wlo + off);
            // independent MFMAs between dependent reuses of the same acc
            #pragma unroll
            for (int mi = 0; mi < 4; ++mi)
                acc[mi][ni] = __builtin_amdgcn_mfma_f32_16x16x32_bf16(ah[mi], bh, acc[mi][ni], 0, 0, 0);
            #pragma unroll
            for (int mi = 0; mi < 4; ++mi)
                acc[mi][ni] = __builtin_amdgcn_mfma_f32_16x16x32_bf16(ah[mi], bl, acc[mi][ni], 0, 0, 0);
            #pragma unroll
            for (int mi = 0; mi < 4; ++mi)
                acc[mi][ni] = __builtin_amdgcn_mfma_f32_16x16x32_bf16(al[mi], bh, acc[mi][ni], 0, 0, 0);
        }
    }

    // ---- epilogue: exchange preacts through LDS in 16-row chunks, gate in fp32 ----
    const size_t OUTS = (size_t)NROWS * 128;
    const int c  = tid & 127;
    const int r0 = tid >> 7;            // 0..3
    const float bic = bi[c], bfc = bfg[c], boc = bo[c], bzc = bz[c];

    #pragma unroll
    for (int mi = 0; mi < 4; ++mi) {
        __syncthreads();   // K-loop LDS reads / previous chunk reads complete
        #pragma unroll
        for (int ni = 0; ni < 4; ++ni) {
            int col = g * 128 + ch * 64 + ni * 16 + l15;
            #pragma unroll
            for (int r = 0; r < 4; ++r)
                pre[(lg * 4 + r) * 512 + col] = acc[mi][ni][r];
        }
        __syncthreads();

        float cp[4], np[4];
        #pragma unroll
        for (int it = 0; it < 4; ++it) {
            int r = r0 + it * 4;
            size_t gidx = (size_t)(row0 + mi * 16 + r) * 128 + c;
            cp[it] = cprev[gidx];
            np[it] = nprev[gidx];
        }
        #pragma unroll
        for (int it = 0; it < 4; ++it) {
            int r = r0 + it * 4;
            size_t gidx = (size_t)(row0 + mi * 16 + r) * 128 + c;
            float pit = pre[r * 512 +         c] + bic;
            float pft = pre[r * 512 + 128 +   c] + bfc;
            float pot = pre[r * 512 + 256 +   c] + boc;
            float pzt = pre[r * 512 + 384 +   c] + bzc;
            float m   = fmaxf(pft, pit);
            float i_t = __expf(pit - m);
            float f_t = 1.0f / (1.0f + __expf(-pft)) + __expf(pft - m);
            float o_t = 1.0f / (1.0f + __expf(-pot));
            float z_t = tanhf(pzt);
            float c_t = f_t * cp[it] + i_t * z_t;
            float n_t = f_t * np[it] + i_t;
            float h_t = o_t * (c_t / (n_t + 1e-8f));
            out[gidx]            = h_t;
            out[OUTS + gidx]     = c_t;
            out[2 * OUTS + gidx] = n_t;
        }
    }
}

extern "C" void kernel_launch(void* const* d_in, const int* in_sizes, int n_in,
                              void* d_out, int out_size, void* d_ws, size_t ws_size,
                              hipStream_t stream) {
    const float* x  = (const float*)d_in[0];
    const float* h  = (const float*)d_in[1];
    const float* cp = (const float*)d_in[2];
    const float* np = (const float*)d_in[3];
    const float* Wi = (const float*)d_in[4];
    const float* Ui = (const float*)d_in[5];
    const float* Wf = (const float*)d_in[6];
    const float* Uf = (const float*)d_in[7];
    const float* Wo = (const float*)d_in[8];
    const float* Uo = (const float*)d_in[9];
    const float* Wz = (const float*)d_in[10];
    const float* Uz = (const float*)d_in[11];
    const float* bi = (const float*)d_in[12];
    const float* bf = (const float*)d_in[13];
    const float* bo = (const float*)d_in[14];
    const float* bz = (const float*)d_in[15];

    ushort* whi = (ushort*)d_ws;                  // 4*128*256 ushorts = 256 KB
    ushort* wlo = whi + 4 * 128 * 256;            // another 256 KB

    prep_weights<<<512, 256, 0, stream>>>(Wi, Ui, Wf, Uf, Wo, Uo, Wz, Uz, whi, wlo);
    slstm_main<<<NBLKS, 512, 0, stream>>>(x, h, cp, np, bi, bf, bo, bz, whi, wlo,
                                          (float*)d_out);
}